// Round 2
// baseline (381.647 us; speedup 1.0000x reference)
//
#include <hip/hip_runtime.h>

#define BB 4
#define CC 3
#define HH 384
#define WW 384
#define FF 5
#define KK 25   // FF*FF
#define HW (HH*WW)
#define WQ (WW/4)

// Pre-pass: transpose (B,C,H,W) -> (B,H*W) of float4 {c0,c1,c2,0}
__global__ __launch_bounds__(256) void transpose_kernel(
    const float* __restrict__ inp, float4* __restrict__ wsin)
{
    int idx = blockIdx.x * blockDim.x + threadIdx.x;
    if (idx >= BB * HW) return;
    int b = idx / HW;
    int i = idx - b * HW;
    const float* base = inp + (size_t)b * CC * HW + i;
    float4 v;
    v.x = base[0];
    v.y = base[HW];
    v.z = base[2 * HW];
    v.w = 0.f;
    wsin[idx] = v;
}

__global__ __launch_bounds__(256) void dsepconv_kernel(
    const float4* __restrict__ wsin,
    const float* __restrict__ vert,
    const float* __restrict__ horiz,
    const float* __restrict__ offx,
    const float* __restrict__ offy,
    const float* __restrict__ mask,
    float* __restrict__ out)
{
    int t = blockIdx.x * blockDim.x + threadIdx.x;   // quad index over BB*HW/4
    if (t >= BB * (HW / 4)) return;
    int xq = t % WQ;
    int y  = (t / WQ) % HH;
    int b  = t / (HW / 4);
    int xb = xq * 4;                 // base x of this thread's 4 pixels
    int planeoff = y * WW + xb;      // 16B aligned

    // Per-pixel separable weights: v4[f] holds vert[f] for the 4 pixels
    float4 v4[FF], h4[FF];
#pragma unroll
    for (int f = 0; f < FF; ++f) {
        v4[f] = *(const float4*)(vert  + ((size_t)(b * FF + f)) * HW + planeoff);
        h4[f] = *(const float4*)(horiz + ((size_t)(b * FF + f)) * HW + planeoff);
    }

    const float4* in_b = wsin + (size_t)b * HW;

    float4 acc[4];
#pragma unroll
    for (int p = 0; p < 4; ++p) acc[p] = make_float4(0.f, 0.f, 0.f, 0.f);

    const float fy = (float)y;

    for (int ki = 0; ki < FF; ++ki) {
        float dy = fy + (float)(ki - 2);
        const float* va = (const float*)&v4[ki];
#pragma unroll
        for (int kj = 0; kj < FF; ++kj) {
            int k = ki * FF + kj;
            size_t koff = ((size_t)(b * KK + k)) * HW + planeoff;
            float4 ox4 = *(const float4*)(offx + koff);
            float4 oy4 = *(const float4*)(offy + koff);
            float4 m4  = *(const float4*)(mask + koff);
            const float* oxa = (const float*)&ox4;
            const float* oya = (const float*)&oy4;
            const float* ma  = (const float*)&m4;
            const float* ha  = (const float*)&h4[kj];
#pragma unroll
            for (int p = 0; p < 4; ++p) {
                float py = oya[p] + dy;
                float px = oxa[p] + (float)(xb + p + kj - 2);
                py = fminf(fmaxf(py, 0.f), (float)(HH - 1));
                px = fminf(fmaxf(px, 0.f), (float)(WW - 1));
                float y0f = floorf(py);
                float x0f = floorf(px);
                float wy = py - y0f;
                float wx = px - x0f;
                int y0 = (int)y0f;
                int x0 = (int)x0f;
                int y1 = min(y0 + 1, HH - 1);
                int x1 = min(x0 + 1, WW - 1);

                float4 g00 = in_b[y0 * WW + x0];
                float4 g01 = in_b[y0 * WW + x1];
                float4 g10 = in_b[y1 * WW + x0];
                float4 g11 = in_b[y1 * WW + x1];

                float w00 = (1.f - wy) * (1.f - wx);
                float w01 = (1.f - wy) * wx;
                float w10 = wy * (1.f - wx);
                float w11 = wy * wx;
                float wt  = va[p] * ha[p] * ma[p];

                acc[p].x += wt * (g00.x * w00 + g01.x * w01 + g10.x * w10 + g11.x * w11);
                acc[p].y += wt * (g00.y * w00 + g01.y * w01 + g10.y * w10 + g11.y * w11);
                acc[p].z += wt * (g00.z * w00 + g01.z * w01 + g10.z * w10 + g11.z * w11);
            }
        }
    }

    // Store: per channel, 4 consecutive pixels as one dwordx4
    float* outb = out + (size_t)b * CC * HW + planeoff;
    float4 oc0 = make_float4(acc[0].x, acc[1].x, acc[2].x, acc[3].x);
    float4 oc1 = make_float4(acc[0].y, acc[1].y, acc[2].y, acc[3].y);
    float4 oc2 = make_float4(acc[0].z, acc[1].z, acc[2].z, acc[3].z);
    *(float4*)(outb)          = oc0;
    *(float4*)(outb + HW)     = oc1;
    *(float4*)(outb + 2 * HW) = oc2;
}

extern "C" void kernel_launch(void* const* d_in, const int* in_sizes, int n_in,
                              void* d_out, int out_size, void* d_ws, size_t ws_size,
                              hipStream_t stream) {
    const float* inp   = (const float*)d_in[0];
    const float* vert  = (const float*)d_in[1];
    const float* horiz = (const float*)d_in[2];
    const float* offx  = (const float*)d_in[3];
    const float* offy  = (const float*)d_in[4];
    const float* mask  = (const float*)d_in[5];
    float* out = (float*)d_out;
    float4* wsin = (float4*)d_ws;   // BB*HW float4 = 9.4 MB

    {
        int total = BB * HW;
        transpose_kernel<<<(total + 255) / 256, 256, 0, stream>>>(inp, wsin);
    }
    {
        int total = BB * (HW / 4);
        dsepconv_kernel<<<(total + 255) / 256, 256, 0, stream>>>(
            wsin, vert, horiz, offx, offy, mask, out);
    }
}

// Round 3
// 315.705 us; speedup vs baseline: 1.2089x; 1.2089x over previous
//
#include <hip/hip_runtime.h>

#define BB 4
#define CC 3
#define HH 384
#define WW 384
#define FF 5
#define KK 25   // FF*FF
#define HW (HH*WW)

// Pre-pass: (B,C,H,W) planar -> (B,H*W) of float4 {c0,c1,c2,0}, fully vectorized
__global__ __launch_bounds__(256) void transpose_kernel(
    const float* __restrict__ inp, float4* __restrict__ wsin)
{
    int t = blockIdx.x * blockDim.x + threadIdx.x;   // quad index
    if (t >= BB * (HW / 4)) return;
    int b = t / (HW / 4);
    int i = (t - b * (HW / 4)) * 4;
    const float* base = inp + (size_t)b * CC * HW + i;
    float4 c0 = *(const float4*)(base);
    float4 c1 = *(const float4*)(base + HW);
    float4 c2 = *(const float4*)(base + 2 * HW);
    float4* o = wsin + (size_t)b * HW + i;
    o[0] = make_float4(c0.x, c1.x, c2.x, 0.f);
    o[1] = make_float4(c0.y, c1.y, c2.y, 0.f);
    o[2] = make_float4(c0.z, c1.z, c2.z, 0.f);
    o[3] = make_float4(c0.w, c1.w, c2.w, 0.f);
}

// One thread per (b,y,x) pixel; gathers are single float4 loads (3 channels packed)
__global__ __launch_bounds__(256, 5) void dsepconv_kernel(
    const float4* __restrict__ wsin,
    const float* __restrict__ vert,
    const float* __restrict__ horiz,
    const float* __restrict__ offx,
    const float* __restrict__ offy,
    const float* __restrict__ mask,
    float* __restrict__ out)
{
    int idx = blockIdx.x * blockDim.x + threadIdx.x;
    if (idx >= BB * HW) return;
    int x = idx % WW;
    int y = (idx / WW) % HH;
    int b = idx / HW;
    int planeoff = y * WW + x;

    float v[FF], hz[FF];
#pragma unroll
    for (int f = 0; f < FF; ++f) {
        v[f]  = vert [(b * FF + f) * HW + planeoff];
        hz[f] = horiz[(b * FF + f) * HW + planeoff];
    }

    const float4* in_b = wsin + (size_t)b * HW;

    float acc0 = 0.f, acc1 = 0.f, acc2 = 0.f;
    const float fy = (float)y;
    const float fx = (float)x;

    for (int ki = 0; ki < FF; ++ki) {
        float vki = v[ki];
        float dy  = fy + (float)(ki - 2);
        const float* ox_p = offx + (size_t)(b * KK + ki * FF) * HW + planeoff;
        const float* oy_p = offy + (size_t)(b * KK + ki * FF) * HW + planeoff;
        const float* m_p  = mask + (size_t)(b * KK + ki * FF) * HW + planeoff;
#pragma unroll
        for (int kj = 0; kj < FF; ++kj) {
            float ox = ox_p[kj * HW];
            float oy = oy_p[kj * HW];
            float m  = m_p [kj * HW];
            float wt = vki * hz[kj] * m;

            float py = oy + dy;
            float px = ox + fx + (float)(kj - 2);
            py = fminf(fmaxf(py, 0.f), (float)(HH - 1));
            px = fminf(fmaxf(px, 0.f), (float)(WW - 1));
            float y0f = floorf(py);
            float x0f = floorf(px);
            float wy = py - y0f;
            float wx = px - x0f;
            int y0 = (int)y0f;
            int x0 = (int)x0f;
            int y1 = min(y0 + 1, HH - 1);
            int x1 = min(x0 + 1, WW - 1);

            float4 g00 = in_b[y0 * WW + x0];
            float4 g01 = in_b[y0 * WW + x1];
            float4 g10 = in_b[y1 * WW + x0];
            float4 g11 = in_b[y1 * WW + x1];

            float w00 = (1.f - wy) * (1.f - wx);
            float w01 = (1.f - wy) * wx;
            float w10 = wy * (1.f - wx);
            float w11 = wy * wx;

            acc0 += wt * (g00.x * w00 + g01.x * w01 + g10.x * w10 + g11.x * w11);
            acc1 += wt * (g00.y * w00 + g01.y * w01 + g10.y * w10 + g11.y * w11);
            acc2 += wt * (g00.z * w00 + g01.z * w01 + g10.z * w10 + g11.z * w11);
        }
    }

    out[(b * CC + 0) * HW + planeoff] = acc0;
    out[(b * CC + 1) * HW + planeoff] = acc1;
    out[(b * CC + 2) * HW + planeoff] = acc2;
}

extern "C" void kernel_launch(void* const* d_in, const int* in_sizes, int n_in,
                              void* d_out, int out_size, void* d_ws, size_t ws_size,
                              hipStream_t stream) {
    const float* inp   = (const float*)d_in[0];
    const float* vert  = (const float*)d_in[1];
    const float* horiz = (const float*)d_in[2];
    const float* offx  = (const float*)d_in[3];
    const float* offy  = (const float*)d_in[4];
    const float* mask  = (const float*)d_in[5];
    float* out = (float*)d_out;
    float4* wsin = (float4*)d_ws;   // BB*HW float4 = 9.4 MB scratch

    {
        int total = BB * (HW / 4);
        transpose_kernel<<<(total + 255) / 256, 256, 0, stream>>>(inp, wsin);
    }
    {
        int total = BB * HW;
        dsepconv_kernel<<<(total + 255) / 256, 256, 0, stream>>>(
            wsin, vert, horiz, offx, offy, mask, out);
    }
}

// Round 5
// 253.801 us; speedup vs baseline: 1.5037x; 1.2439x over previous
//
#include <hip/hip_runtime.h>

#define BB 4
#define CC 3
#define HH 384
#define WW 384
#define FF 5
#define KK 25   // FF*FF
#define HW (HH*WW)

#define TX 32   // tile width  (pixels)
#define TY 8    // tile height (pixels)

typedef float fx4 __attribute__((ext_vector_type(4)));

__device__ __forceinline__ fx4 nt_load4(const float* p) {
    return __builtin_nontemporal_load((const fx4*)p);
}

// Pre-pass: (B,C,H,W) planar -> (B,H*W) of float4 {c0,c1,c2,0}, fully vectorized
__global__ __launch_bounds__(256) void transpose_kernel(
    const float* __restrict__ inp, float4* __restrict__ wsin)
{
    int t = blockIdx.x * blockDim.x + threadIdx.x;   // quad index
    if (t >= BB * (HW / 4)) return;
    int b = t / (HW / 4);
    int i = (t - b * (HW / 4)) * 4;
    const float* base = inp + (size_t)b * CC * HW + i;
    fx4 c0 = nt_load4(base);
    fx4 c1 = nt_load4(base + HW);
    fx4 c2 = nt_load4(base + 2 * HW);
    float4* o = wsin + (size_t)b * HW + i;
    o[0] = make_float4(c0.x, c1.x, c2.x, 0.f);
    o[1] = make_float4(c0.y, c1.y, c2.y, 0.f);
    o[2] = make_float4(c0.z, c1.z, c2.z, 0.f);
    o[3] = make_float4(c0.w, c1.w, c2.w, 0.f);
}

// One thread per pixel; block covers a 32x8 tile so the bilinear-gather
// working set (~14 KB of channel-packed float4) fits in the 32 KB L1.
// All read-once streams use nontemporal loads to keep L1 for the gathers.
__global__ __launch_bounds__(256) void dsepconv_kernel(
    const float4* __restrict__ wsin,
    const float* __restrict__ vert,
    const float* __restrict__ horiz,
    const float* __restrict__ offx,
    const float* __restrict__ offy,
    const float* __restrict__ mask,
    float* __restrict__ out)
{
    int tx = threadIdx.x & (TX - 1);
    int ty = threadIdx.x / TX;
    int x = blockIdx.x * TX + tx;
    int y = blockIdx.y * TY + ty;
    int b = blockIdx.z;
    int planeoff = y * WW + x;

    float v[FF], hz[FF];
#pragma unroll
    for (int f = 0; f < FF; ++f) {
        v[f]  = __builtin_nontemporal_load(vert  + (b * FF + f) * HW + planeoff);
        hz[f] = __builtin_nontemporal_load(horiz + (b * FF + f) * HW + planeoff);
    }

    const float4* in_b = wsin + (size_t)b * HW;

    float acc0 = 0.f, acc1 = 0.f, acc2 = 0.f;
    const float fy = (float)y;
    const float fx = (float)x;

    for (int ki = 0; ki < FF; ++ki) {
        float vki = v[ki];
        float dy  = fy + (float)(ki - 2);
        const float* ox_p = offx + (size_t)(b * KK + ki * FF) * HW + planeoff;
        const float* oy_p = offy + (size_t)(b * KK + ki * FF) * HW + planeoff;
        const float* m_p  = mask + (size_t)(b * KK + ki * FF) * HW + planeoff;
#pragma unroll
        for (int kj = 0; kj < FF; ++kj) {
            float ox = __builtin_nontemporal_load(ox_p + kj * HW);
            float oy = __builtin_nontemporal_load(oy_p + kj * HW);
            float m  = __builtin_nontemporal_load(m_p  + kj * HW);
            float wt = vki * hz[kj] * m;

            float py = oy + dy;
            float px = ox + fx + (float)(kj - 2);
            py = fminf(fmaxf(py, 0.f), (float)(HH - 1));
            px = fminf(fmaxf(px, 0.f), (float)(WW - 1));
            float y0f = floorf(py);
            float x0f = floorf(px);
            float wy = py - y0f;
            float wx = px - x0f;
            int y0 = (int)y0f;
            int x0 = (int)x0f;
            int y1 = min(y0 + 1, HH - 1);
            int x1 = min(x0 + 1, WW - 1);

            float4 g00 = in_b[y0 * WW + x0];
            float4 g01 = in_b[y0 * WW + x1];
            float4 g10 = in_b[y1 * WW + x0];
            float4 g11 = in_b[y1 * WW + x1];

            float w00 = (1.f - wy) * (1.f - wx);
            float w01 = (1.f - wy) * wx;
            float w10 = wy * (1.f - wx);
            float w11 = wy * wx;

            acc0 += wt * (g00.x * w00 + g01.x * w01 + g10.x * w10 + g11.x * w11);
            acc1 += wt * (g00.y * w00 + g01.y * w01 + g10.y * w10 + g11.y * w11);
            acc2 += wt * (g00.z * w00 + g01.z * w01 + g10.z * w10 + g11.z * w11);
        }
    }

    out[(b * CC + 0) * HW + planeoff] = acc0;
    out[(b * CC + 1) * HW + planeoff] = acc1;
    out[(b * CC + 2) * HW + planeoff] = acc2;
}

extern "C" void kernel_launch(void* const* d_in, const int* in_sizes, int n_in,
                              void* d_out, int out_size, void* d_ws, size_t ws_size,
                              hipStream_t stream) {
    const float* inp   = (const float*)d_in[0];
    const float* vert  = (const float*)d_in[1];
    const float* horiz = (const float*)d_in[2];
    const float* offx  = (const float*)d_in[3];
    const float* offy  = (const float*)d_in[4];
    const float* mask  = (const float*)d_in[5];
    float* out = (float*)d_out;
    float4* wsin = (float4*)d_ws;   // BB*HW float4 = 9.4 MB scratch

    {
        int total = BB * (HW / 4);
        transpose_kernel<<<(total + 255) / 256, 256, 0, stream>>>(inp, wsin);
    }
    {
        dim3 grid(WW / TX, HH / TY, BB);   // 12 x 48 x 4
        dsepconv_kernel<<<grid, 256, 0, stream>>>(
            wsin, vert, horiz, offx, offy, mask, out);
    }
}

// Round 6
// 231.923 us; speedup vs baseline: 1.6456x; 1.0943x over previous
//
#include <hip/hip_runtime.h>
#include <hip/hip_fp16.h>

#define BB 4
#define CC 3
#define HH 384
#define WW 384
#define FF 5
#define KK 25            // FF*FF
#define HW (HH*WW)
#define WP 192           // 16B entries per row (2 pixels each)
#define TOT (BB*HH*WP)   // entries per table copy

#define TX 32            // tile width  (pixels)
#define TY 8             // tile height (pixels)

// pack one pixel (3 fp32 channels) -> 8B: dword0 = h(c0) | h(c1)<<16, dword1 = h(c2)
__device__ __forceinline__ uint2 pack_px(float c0, float c1, float c2) {
    __half2 h01 = __floats2half2_rn(c0, c1);
    uint2 r;
    r.x = *(const unsigned int*)&h01;
    r.y = (unsigned int)__half_as_ushort(__float2half_rn(c2));
    return r;
}

// Pre-pass: build dual fp16 pixel-pair tables.
// copy A entry j = pixels (2j, 2j+1); copy B entry j = pixels (2j+1, 2j+2 clamped).
// Any bilinear x-corner pair (x0, min(x0+1,383)) is ONE aligned 16B entry:
// index j = x0>>1, copy = x0&1.
__global__ __launch_bounds__(256) void pack_kernel(
    const float* __restrict__ inp, uint4* __restrict__ tab)
{
    int t = blockIdx.x * blockDim.x + threadIdx.x;
    if (t >= TOT) return;
    int j = t % WP;
    int y = (t / WP) % HH;
    int b = t / (WP * HH);
    int p0 = 2 * j, p1 = 2 * j + 1, p2 = min(2 * j + 2, WW - 1);
    const float* b0 = inp + (((size_t)b * CC + 0) * HH + y) * WW;
    const float* b1 = inp + (((size_t)b * CC + 1) * HH + y) * WW;
    const float* b2 = inp + (((size_t)b * CC + 2) * HH + y) * WW;
    uint2 q0 = pack_px(b0[p0], b1[p0], b2[p0]);
    uint2 q1 = pack_px(b0[p1], b1[p1], b2[p1]);
    uint2 q2 = pack_px(b0[p2], b1[p2], b2[p2]);
    tab[t]       = make_uint4(q0.x, q0.y, q1.x, q1.y);   // copy A
    tab[TOT + t] = make_uint4(q1.x, q1.y, q2.x, q2.y);   // copy B
}

__device__ __forceinline__ void unpack_pair(uint4 r,
    float& lo0, float& lo1, float& lo2, float& hi0, float& hi1, float& hi2)
{
    float2 lo01 = __half22float2(*(const __half2*)&r.x);
    float2 hi01 = __half22float2(*(const __half2*)&r.z);
    lo0 = lo01.x; lo1 = lo01.y;
    hi0 = hi01.x; hi1 = hi01.y;
    lo2 = __half2float(*(const __half*)&r.y);
    hi2 = __half2float(*(const __half*)&r.w);
}

// One thread per pixel; 32x8 tile per block (gather working set fits L1).
// Per tap: 2 divergent 16B gathers (row y0 pair, row y1 pair) instead of 4.
__global__ __launch_bounds__(256) void dsepconv_kernel(
    const uint4* __restrict__ tab,
    const float* __restrict__ vert,
    const float* __restrict__ horiz,
    const float* __restrict__ offx,
    const float* __restrict__ offy,
    const float* __restrict__ mask,
    float* __restrict__ out)
{
    int tx = threadIdx.x & (TX - 1);
    int ty = threadIdx.x / TX;
    int x = blockIdx.x * TX + tx;
    int y = blockIdx.y * TY + ty;
    int b = blockIdx.z;
    int planeoff = y * WW + x;

    float v[FF], hz[FF];
#pragma unroll
    for (int f = 0; f < FF; ++f) {
        v[f]  = __builtin_nontemporal_load(vert  + (b * FF + f) * HW + planeoff);
        hz[f] = __builtin_nontemporal_load(horiz + (b * FF + f) * HW + planeoff);
    }

    const uint4* tb = tab + (size_t)b * (HH * WP);   // copy A base for this batch

    float acc0 = 0.f, acc1 = 0.f, acc2 = 0.f;
    const float fy = (float)y;
    const float fx = (float)x;

    for (int ki = 0; ki < FF; ++ki) {
        float vki = v[ki];
        float dy  = fy + (float)(ki - 2);
        const float* ox_p = offx + (size_t)(b * KK + ki * FF) * HW + planeoff;
        const float* oy_p = offy + (size_t)(b * KK + ki * FF) * HW + planeoff;
        const float* m_p  = mask + (size_t)(b * KK + ki * FF) * HW + planeoff;
#pragma unroll
        for (int kj = 0; kj < FF; ++kj) {
            float ox = __builtin_nontemporal_load(ox_p + kj * HW);
            float oy = __builtin_nontemporal_load(oy_p + kj * HW);
            float m  = __builtin_nontemporal_load(m_p  + kj * HW);
            float wt = vki * hz[kj] * m;

            float py = oy + dy;
            float px = ox + fx + (float)(kj - 2);
            py = fminf(fmaxf(py, 0.f), (float)(HH - 1));
            px = fminf(fmaxf(px, 0.f), (float)(WW - 1));
            float y0f = floorf(py);
            float x0f = floorf(px);
            float wy = py - y0f;
            float wx = px - x0f;
            int y0 = (int)y0f;
            int x0 = (int)x0f;
            int y1 = min(y0 + 1, HH - 1);

            int j    = x0 >> 1;
            int selo = (x0 & 1) ? TOT : 0;      // copy B if x0 odd
            const uint4* tbs = tb + selo;
            uint4 r0 = tbs[y0 * WP + j];
            uint4 r1 = tbs[y1 * WP + j];

            float a00, a01, a02, b00, b01, b02;
            float a10, a11, a12, b10, b11, b12;
            unpack_pair(r0, a00, a01, a02, b00, b01, b02);
            unpack_pair(r1, a10, a11, a12, b10, b11, b12);

            float w00 = (1.f - wy) * (1.f - wx);
            float w01 = (1.f - wy) * wx;
            float w10 = wy * (1.f - wx);
            float w11 = wy * wx;

            acc0 += wt * (a00 * w00 + b00 * w01 + a10 * w10 + b10 * w11);
            acc1 += wt * (a01 * w00 + b01 * w01 + a11 * w10 + b11 * w11);
            acc2 += wt * (a02 * w00 + b02 * w01 + a12 * w10 + b12 * w11);
        }
    }

    out[(b * CC + 0) * HW + planeoff] = acc0;
    out[(b * CC + 1) * HW + planeoff] = acc1;
    out[(b * CC + 2) * HW + planeoff] = acc2;
}

extern "C" void kernel_launch(void* const* d_in, const int* in_sizes, int n_in,
                              void* d_out, int out_size, void* d_ws, size_t ws_size,
                              hipStream_t stream) {
    const float* inp   = (const float*)d_in[0];
    const float* vert  = (const float*)d_in[1];
    const float* horiz = (const float*)d_in[2];
    const float* offx  = (const float*)d_in[3];
    const float* offy  = (const float*)d_in[4];
    const float* mask  = (const float*)d_in[5];
    float* out = (float*)d_out;
    uint4* tab = (uint4*)d_ws;   // 2 copies x 4.72 MB = 9.44 MB

    {
        pack_kernel<<<(TOT + 255) / 256, 256, 0, stream>>>(inp, tab);
    }
    {
        dim3 grid(WW / TX, HH / TY, BB);   // 12 x 48 x 4
        dsepconv_kernel<<<grid, 256, 0, stream>>>(
            tab, vert, horiz, offx, offy, mask, out);
    }
}

// Round 7
// 219.799 us; speedup vs baseline: 1.7363x; 1.0552x over previous
//
#include <hip/hip_runtime.h>
#include <hip/hip_fp16.h>

#define BB 4
#define CC 3
#define HH 384
#define WW 384
#define FF 5
#define KK 25            // FF*FF
#define HW (HH*WW)
#define WP 192           // 16B pair-entries per row
#define TOT (BB*HH*WP)   // entries per table copy

#define TX 64            // tile width (pixels) — 32 threads x 2 px
#define TY 8             // tile height

typedef float fx2 __attribute__((ext_vector_type(2)));

__device__ __forceinline__ fx2 nt_load2(const float* p) {
    return __builtin_nontemporal_load((const fx2*)p);
}

// pack one pixel (3 fp32 channels) -> 8B: dword0 = h(c0)|h(c1)<<16, dword1 = h(c2)
__device__ __forceinline__ uint2 pack_px(float c0, float c1, float c2) {
    __half2 h01 = __floats2half2_rn(c0, c1);
    uint2 r;
    r.x = *(const unsigned int*)&h01;
    r.y = (unsigned int)__half_as_ushort(__float2half_rn(c2));
    return r;
}

// Dual fp16 pixel-pair tables: copy A entry j = pixels (2j,2j+1);
// copy B entry j = (2j+1, 2j+2 clamped). Corner pair (x0,x0+1) = one
// aligned 16B entry: j = x0>>1, copy = x0&1.
__global__ __launch_bounds__(256) void pack_kernel(
    const float* __restrict__ inp, uint4* __restrict__ tab)
{
    int t = blockIdx.x * blockDim.x + threadIdx.x;
    if (t >= TOT) return;
    int j = t % WP;
    int y = (t / WP) % HH;
    int b = t / (WP * HH);
    int p0 = 2 * j, p1 = 2 * j + 1, p2 = min(2 * j + 2, WW - 1);
    const float* b0 = inp + (((size_t)b * CC + 0) * HH + y) * WW;
    const float* b1 = inp + (((size_t)b * CC + 1) * HH + y) * WW;
    const float* b2 = inp + (((size_t)b * CC + 2) * HH + y) * WW;
    uint2 q0 = pack_px(b0[p0], b1[p0], b2[p0]);
    uint2 q1 = pack_px(b0[p1], b1[p1], b2[p1]);
    uint2 q2 = pack_px(b0[p2], b1[p2], b2[p2]);
    tab[t]       = make_uint4(q0.x, q0.y, q1.x, q1.y);   // copy A
    tab[TOT + t] = make_uint4(q1.x, q1.y, q2.x, q2.y);   // copy B
}

__device__ __forceinline__ void unpack_pair(uint4 r,
    float& lo0, float& lo1, float& lo2, float& hi0, float& hi1, float& hi2)
{
    float2 lo01 = __half22float2(*(const __half2*)&r.x);
    float2 hi01 = __half22float2(*(const __half2*)&r.z);
    lo0 = lo01.x; lo1 = lo01.y;
    hi0 = hi01.x; hi1 = hi01.y;
    lo2 = __half2float(*(const __half*)&r.y);
    hi2 = __half2float(*(const __half*)&r.w);
}

// 2 adjacent pixels per thread: all streaming loads become dwordx2.
// 64x8 tile per block; gathers stay 2x16B per tap per pixel.
__global__ __launch_bounds__(256) void dsepconv_kernel(
    const uint4* __restrict__ tab,
    const float* __restrict__ vert,
    const float* __restrict__ horiz,
    const float* __restrict__ offx,
    const float* __restrict__ offy,
    const float* __restrict__ mask,
    float* __restrict__ out)
{
    int tx = threadIdx.x & 31;
    int ty = threadIdx.x >> 5;
    int xb = blockIdx.x * TX + tx * 2;      // even
    int y  = blockIdx.y * TY + ty;
    int b  = blockIdx.z;
    int planeoff = y * WW + xb;             // 8B aligned

    fx2 v2[FF], h2[FF];
#pragma unroll
    for (int f = 0; f < FF; ++f) {
        v2[f] = nt_load2(vert  + (b * FF + f) * HW + planeoff);
        h2[f] = nt_load2(horiz + (b * FF + f) * HW + planeoff);
    }

    const uint4* tb = tab + (size_t)b * (HH * WP);

    float acc[2][3] = {{0.f,0.f,0.f},{0.f,0.f,0.f}};
    const float fy = (float)y;

    for (int ki = 0; ki < FF; ++ki) {
        float dy = fy + (float)(ki - 2);
        const float* ox_p = offx + (size_t)(b * KK + ki * FF) * HW + planeoff;
        const float* oy_p = offy + (size_t)(b * KK + ki * FF) * HW + planeoff;
        const float* m_p  = mask + (size_t)(b * KK + ki * FF) * HW + planeoff;
#pragma unroll
        for (int kj = 0; kj < FF; ++kj) {
            fx2 ox2 = nt_load2(ox_p + kj * HW);
            fx2 oy2 = nt_load2(oy_p + kj * HW);
            fx2 m2  = nt_load2(m_p  + kj * HW);
#pragma unroll
            for (int p = 0; p < 2; ++p) {
                float wt = v2[ki][p] * h2[kj][p] * m2[p];
                float py = oy2[p] + dy;
                float px = ox2[p] + (float)(xb + p + kj - 2);
                py = fminf(fmaxf(py, 0.f), (float)(HH - 1));
                px = fminf(fmaxf(px, 0.f), (float)(WW - 1));
                float y0f = floorf(py);
                float x0f = floorf(px);
                float wy = py - y0f;
                float wx = px - x0f;
                int y0 = (int)y0f;
                int x0 = (int)x0f;
                int y1 = min(y0 + 1, HH - 1);

                int j    = x0 >> 1;
                const uint4* tbs = tb + ((x0 & 1) ? TOT : 0);
                uint4 r0 = tbs[y0 * WP + j];
                uint4 r1 = tbs[y1 * WP + j];

                float a00,a01,a02,b00,b01,b02;
                float a10,a11,a12,b10,b11,b12;
                unpack_pair(r0, a00,a01,a02, b00,b01,b02);
                unpack_pair(r1, a10,a11,a12, b10,b11,b12);

                float w00 = (1.f - wy) * (1.f - wx);
                float w01 = (1.f - wy) * wx;
                float w10 = wy * (1.f - wx);
                float w11 = wy * wx;

                acc[p][0] += wt * (a00*w00 + b00*w01 + a10*w10 + b10*w11);
                acc[p][1] += wt * (a01*w00 + b01*w01 + a11*w10 + b11*w11);
                acc[p][2] += wt * (a02*w00 + b02*w01 + a12*w10 + b12*w11);
            }
        }
    }

#pragma unroll
    for (int c = 0; c < CC; ++c) {
        fx2 o; o.x = acc[0][c]; o.y = acc[1][c];
        *(fx2*)(out + ((size_t)b * CC + c) * HW + planeoff) = o;
    }
}

extern "C" void kernel_launch(void* const* d_in, const int* in_sizes, int n_in,
                              void* d_out, int out_size, void* d_ws, size_t ws_size,
                              hipStream_t stream) {
    const float* inp   = (const float*)d_in[0];
    const float* vert  = (const float*)d_in[1];
    const float* horiz = (const float*)d_in[2];
    const float* offx  = (const float*)d_in[3];
    const float* offy  = (const float*)d_in[4];
    const float* mask  = (const float*)d_in[5];
    float* out = (float*)d_out;
    uint4* tab = (uint4*)d_ws;   // 2 x 4.72 MB

    {
        pack_kernel<<<(TOT + 255) / 256, 256, 0, stream>>>(inp, tab);
    }
    {
        dim3 grid(WW / TX, HH / TY, BB);   // 6 x 48 x 4
        dsepconv_kernel<<<grid, 256, 0, stream>>>(
            tab, vert, horiz, offx, offy, mask, out);
    }
}